// Round 3
// baseline (286.403 us; speedup 1.0000x reference)
//
#include <hip/hip_runtime.h>
#include <hip/hip_bf16.h>

#define B_ 8
#define G_ 256
#define N_ 1024
#define P_ 4
#define F_ 256
#define KHOP 4
#define KG_ (KHOP * G_)   // 1024

typedef unsigned short ushort_t;
typedef __bf16 bf16x8 __attribute__((ext_vector_type(8)));
typedef unsigned short u16x8 __attribute__((ext_vector_type(8)));
typedef float f32x4 __attribute__((ext_vector_type(4)));

__device__ __forceinline__ unsigned short f2bf(float f) {
  union { float fl; unsigned int i; } v; v.fl = f;
  return (unsigned short)((v.i + 0x7fffu + ((v.i >> 16) & 1u)) >> 16);
}

__device__ __forceinline__ void gload_lds16(const ushort_t* g, ushort_t* l) {
  __builtin_amdgcn_global_load_lds(
      (const __attribute__((address_space(1))) void*)g,
      (__attribute__((address_space(3))) void*)l, 16, 0, 0);
}

// ---------------------------------------------------------------------------
// K-PREP: one kernel, block-range partitioned.  (unchanged)
__global__ __launch_bounds__(256) void k_prep(
    const float* __restrict__ x, const float* __restrict__ mixer,
    const float* __restrict__ weight, const float* __restrict__ wb,
    const float* __restrict__ fw, float* __restrict__ e1, float* __restrict__ e2,
    ushort_t* __restrict__ fwbf, ushort_t* __restrict__ xT,
    float* __restrict__ sumb) {
  int blk = blockIdx.x;
  int t = threadIdx.x;
  if (blk < 128) {
    __shared__ float s1[G_], s2[G_];
    __shared__ float cred[2][4];
    int bp = blk >> 2;
    int nc = blk & 3;
    int b = bp >> 2, p = bp & (P_ - 1);
    int n = nc * 256 + t;
    float acc1 = 0.f, acc2 = 0.f;
    const float* wp = weight + (size_t)p * F_ * G_ + t;
    const float* mp = mixer + p * 2 * F_;
    for (int f = 0; f < F_; ++f) {
      float wv = wp[(size_t)f * G_];
      acc1 = fmaf(mp[f], wv, acc1);
      acc2 = fmaf(mp[F_ + f], wv, acc2);
    }
    s1[t] = acc1;
    s2[t] = acc2;
    float c1p = mp[t] * wb[p * F_ + t];
    float c2p = mp[F_ + t] * wb[p * F_ + t];
#pragma unroll
    for (int mask = 1; mask < 64; mask <<= 1) {
      c1p += __shfl_xor(c1p, mask, 64);
      c2p += __shfl_xor(c2p, mask, 64);
    }
    if ((t & 63) == 0) {
      cred[0][t >> 6] = c1p;
      cred[1][t >> 6] = c2p;
    }
    __syncthreads();
    float c1 = cred[0][0] + cred[0][1] + cred[0][2] + cred[0][3];
    float c2 = cred[1][0] + cred[1][1] + cred[1][2] + cred[1][3];
    const float* xb = x + (size_t)b * G_ * N_ + n;
    float a1 = 0.f, a2 = 0.f;
#pragma unroll 8
    for (int g = 0; g < G_; ++g) {
      float xv = xb[(size_t)g * N_];
      a1 = fmaf(s1[g], xv, a1);
      a2 = fmaf(s2[g], xv, a2);
    }
    e1[(size_t)bp * N_ + n] = c1 + a1;
    e2[(size_t)bp * N_ + n] = c2 + a2;
  } else if (blk < 128 + 1024) {
    int i = (blk - 128) * 1024 + t * 4;
    float4 v = *(const float4*)&fw[i];
    ushort4 o;
    o.x = f2bf(v.x); o.y = f2bf(v.y); o.z = f2bf(v.z); o.w = f2bf(v.w);
    *(ushort4*)&fwbf[i] = o;
  } else if (blk < 1152 + 512) {
    __shared__ ushort_t tile[64][66];
    int idx = blk - 1152;
    int n0 = (idx & 15) * 64;
    int g0 = ((idx >> 4) & 3) * 64;
    int b = idx >> 6;
    int rr = t >> 4, cc = (t & 15) * 4;
#pragma unroll
    for (int ps = 0; ps < 4; ++ps) {
      float4 v = *(const float4*)&x[((size_t)b * G_ + g0 + ps * 16 + rr) * N_ + n0 + cc];
      tile[ps * 16 + rr][cc] = f2bf(v.x);
      tile[ps * 16 + rr][cc + 1] = f2bf(v.y);
      tile[ps * 16 + rr][cc + 2] = f2bf(v.z);
      tile[ps * 16 + rr][cc + 3] = f2bf(v.w);
    }
    __syncthreads();
#pragma unroll
    for (int ps = 0; ps < 4; ++ps) {
      int nl = ps * 16 + rr;
      int gl = cc;
      ushort4 o;
      o.x = tile[gl][nl];
      o.y = tile[gl + 1][nl];
      o.z = tile[gl + 2][nl];
      o.w = tile[gl + 3][nl];
      *(ushort4*)&xT[((size_t)b * N_ + n0 + nl) * G_ + g0 + gl] = o;
    }
  } else {
    int i = (blk - 1664) * 256 + t;
    sumb[i] = 0.f;
  }
}

// ---------------------------------------------------------------------------
// K5: attention, UNNORMALIZED.  (unchanged)
__global__ __launch_bounds__(256) void k_att(const float* __restrict__ e1,
                                             const float* __restrict__ e2,
                                             const float* __restrict__ S,
                                             ushort_t* __restrict__ expT,
                                             float* __restrict__ sumb) {
  __shared__ ushort_t tile[256][72];   // [j-local][i-local]
  __shared__ float se1[256];
  __shared__ float se2[64];
  int bp = blockIdx.z;
  int b = bp >> 2;
  int i0 = blockIdx.y * 64;
  int jt = blockIdx.x;
  int j0 = jt * 256;
  int t = threadIdx.x;
  int rr = t >> 4;
  int cc4 = t & 15;
  int cc = cc4 * 4;

  se1[t] = e1[(size_t)bp * N_ + j0 + t];
  if (t < 64) se2[t] = e2[(size_t)bp * N_ + i0 + t];
  __syncthreads();

  const float* Sb = S + (size_t)b * N_ * N_;
  float re2[4];
#pragma unroll
  for (int ps = 0; ps < 4; ++ps) re2[ps] = se2[ps * 16 + rr];
  float psum[4] = {0.f, 0.f, 0.f, 0.f};
#pragma unroll
  for (int js = 0; js < 4; ++js) {
    float4 e1q = *(float4*)&se1[js * 64 + cc];
    float e1v[4] = {e1q.x, e1q.y, e1q.z, e1q.w};
#pragma unroll
    for (int ps = 0; ps < 4; ++ps) {
      int il = ps * 16 + rr;
      float4 s4 = *(const float4*)&Sb[(size_t)(i0 + il) * N_ + j0 + js * 64 + cc];
      float sv[4] = {s4.x, s4.y, s4.z, s4.w};
#pragma unroll
      for (int s = 0; s < 4; ++s) {
        float v = e1v[s] + re2[ps];
        float l = v >= 0.f ? v : 0.2f * v;
        bool m = fabsf(sv[s]) > 1e-9f;
        float e = m ? __expf(l) : 0.f;
        psum[ps] += e;
        tile[js * 64 + cc + s][il] = f2bf(e);
      }
    }
  }
#pragma unroll
  for (int mask = 1; mask < 16; mask <<= 1) {
#pragma unroll
    for (int ps = 0; ps < 4; ++ps) psum[ps] += __shfl_xor(psum[ps], mask, 64);
  }
  if (cc4 == 0) {
#pragma unroll
    for (int ps = 0; ps < 4; ++ps)
      atomicAdd(&sumb[(size_t)bp * N_ + i0 + ps * 16 + rr], psum[ps]);
  }
  __syncthreads();
  ushort_t* Tb = expT + (size_t)bp * N_ * N_;
  int jl0 = t >> 3;         // 0..31
  int ig = (t & 7) * 8;     // 0..56
#pragma unroll
  for (int pass = 0; pass < 8; ++pass) {
    int jl = pass * 32 + jl0;
    u16x8 v = *(const u16x8*)&tile[jl][ig];
    *(u16x8*)&Tb[(size_t)(j0 + jl) * N_ + i0 + ig] = v;
  }
}

// ---------------------------------------------------------------------------
// K6 v4: Horner step GEMM, 256x128 tile, 8 waves (4M x 2N), BK=64,
// double-buffered 96 KB LDS, 1 block/CU (256 blocks).
//
// FRAG-MAJOR LDS LAYOUT (zero bank conflicts):
//   Tile element (row, k) lives at flat ushort offset
//     ((R*2 + c)*64 + lane)*8 + e,   R = row>>4, c = (k>>5), lane = (k>>3 &3)<<4 | (row&15)
//   i.e. each 16x32 MFMA fragment is a contiguous 1 KB block in exact
//   lane order. ds_read_b128 per fragment = wave-contiguous 1 KB read
//   (structural 8-cycle minimum, no conflicts). Achieved with LINEAR
//   global_load_lds destinations + PERMUTED per-lane global source
//   addresses (rule 21 / m173 pattern).
//
//   Staging: per 8 KB "line" (512 threads x 16 B): thread t stages LDS flat
//   t*8 + line*4096, which decodes to cell = line*8 + w (w = wave), R =
//   cell>>1, c = cell&1; global (row = R*16 + lr, k = ko + c*32 + quad*8).
//
// Pipeline: depth-1-ahead, per iter: stage(next) -> s_waitcnt vmcnt(6)
// (cur tile's 6 per-wave loads done, next's 6 in flight) -> barrier ->
// 2x(8 ds_read + 16 MFMA) -> barrier.  Never drains vmcnt in-loop.
__global__ __launch_bounds__(512, 2) void gemm_step(
    const ushort_t* __restrict__ Aprev, const ushort_t* __restrict__ Bt,
    const ushort_t* __restrict__ fwbf, const ushort_t* __restrict__ xT,
    const float* __restrict__ bias, const float* __restrict__ sumb,
    ushort_t* __restrict__ outb, float* __restrict__ outf,
    int kslice, int has_prev, int last) {
  __shared__ ushort_t As[2][16384];   // 32 KB each buf: 16 R-cells x 2 c x 1 KB
  __shared__ ushort_t Bs[2][8192];    // 16 KB each buf: 8 R-cells x 2 c x 1 KB
  // ---- XCD-aware decode: id&7 = xcd, 4 bps per XCD, 8 n-blocks per bp ----
  int id = blockIdx.x;
  int xcd = id & 7;
  int slot = id >> 3;            // 0..31
  int bp = xcd * 4 + (slot >> 3);
  int n0 = (slot & 7) * 128;
  int p = bp & (P_ - 1), b = bp >> 2;
  int t = threadIdx.x;
  int lane = t & 63;
  int w = t >> 6;                // 0..7
  int wm = w >> 1, wn = w & 1;   // 4M x 2N wave grid
  int lr = lane & 15, quad = lane >> 4;

  // ---- staging source coordinates per line (frag-major permutation) ----
  int rowA[4], colA[4];
#pragma unroll
  for (int l = 0; l < 4; ++l) {
    int cell = l * 8 + w;                 // 0..31
    rowA[l] = (cell >> 1) * 16 + lr;      // 0..255
    colA[l] = (cell & 1) * 32 + quad * 8; // 0..56
  }
  int rowB[2], colB[2];
#pragma unroll
  for (int l = 0; l < 2; ++l) {
    int cell = l * 8 + w;                 // 0..15
    rowB[l] = (cell >> 1) * 16 + lr;      // 0..127
    colB[l] = (cell & 1) * 32 + quad * 8;
  }

  const ushort_t* Abase1 = has_prev ? (Aprev + (size_t)bp * (F_ * N_)) : fwbf;
  const ushort_t* Abase2 = fwbf + (size_t)p * (F_ * KG_) + (size_t)kslice * G_;
  const ushort_t* Bbase1 = Bt + (size_t)bp * N_ * N_;
  const ushort_t* Bbase2 = xT + (size_t)b * (N_ * G_);

  const ushort_t* pA1[4]; const ushort_t* pA2[4];
  const ushort_t* pB1[2]; const ushort_t* pB2[2];
#pragma unroll
  for (int l = 0; l < 4; ++l) {
    pA1[l] = Abase1 + (size_t)rowA[l] * N_ + colA[l];
    pA2[l] = Abase2 + (size_t)rowA[l] * KG_ + colA[l];
  }
#pragma unroll
  for (int l = 0; l < 2; ++l) {
    pB1[l] = Bbase1 + (size_t)(n0 + rowB[l]) * N_ + colB[l];
    pB2[l] = Bbase2 + (size_t)(n0 + rowB[l]) * G_ + colB[l];
  }

  const int ntA = has_prev ? (N_ / 64) : 0;   // 16 or 0
  const int NT = ntA + G_ / 64;               // 20 or 4

  f32x4 acc[4][4] = {};

  auto stage = [&](int it, int buf) {
    if (it < ntA) {
      int ko = it * 64;
#pragma unroll
      for (int l = 0; l < 4; ++l)
        gload_lds16(pA1[l] + ko, &As[buf][l * 4096 + w * 512]);
#pragma unroll
      for (int l = 0; l < 2; ++l)
        gload_lds16(pB1[l] + ko, &Bs[buf][l * 4096 + w * 512]);
    } else {
      int ko = (it - ntA) * 64;
#pragma unroll
      for (int l = 0; l < 4; ++l)
        gload_lds16(pA2[l] + ko, &As[buf][l * 4096 + w * 512]);
#pragma unroll
      for (int l = 0; l < 2; ++l)
        gload_lds16(pB2[l] + ko, &Bs[buf][l * 4096 + w * 512]);
    }
  };

  stage(0, 0);
  int cur = 0;
  for (int it = 0; it < NT; ++it) {
    if (it + 1 < NT) {
      stage(it + 1, cur ^ 1);                          // 6 more in flight
      asm volatile("s_waitcnt vmcnt(6)" ::: "memory"); // cur tile landed
    } else {
      asm volatile("s_waitcnt vmcnt(0)" ::: "memory");
    }
    __builtin_amdgcn_s_barrier();
#pragma unroll
    for (int c = 0; c < 2; ++c) {
      bf16x8 af[4], bfr[4];
#pragma unroll
      for (int mi = 0; mi < 4; ++mi)
        af[mi] = __builtin_bit_cast(bf16x8,
            *(const u16x8*)&As[cur][((wm * 4 + mi) * 2 + c) * 512 + lane * 8]);
#pragma unroll
      for (int ni = 0; ni < 4; ++ni)
        bfr[ni] = __builtin_bit_cast(bf16x8,
            *(const u16x8*)&Bs[cur][((wn * 4 + ni) * 2 + c) * 512 + lane * 8]);
#pragma unroll
      for (int mi = 0; mi < 4; ++mi)
#pragma unroll
        for (int ni = 0; ni < 4; ++ni)
          acc[mi][ni] = __builtin_amdgcn_mfma_f32_16x16x32_bf16(af[mi], bfr[ni], acc[mi][ni], 0, 0, 0);
    }
    __builtin_amdgcn_s_barrier();
    cur ^= 1;
  }

  if (last) {
    float* Ob = outf + (size_t)bp * (F_ * N_);
#pragma unroll
    for (int mi = 0; mi < 4; ++mi) {
      int fbase = wm * 64 + mi * 16 + quad * 4;
#pragma unroll
      for (int ni = 0; ni < 4; ++ni) {
        int n = n0 + wn * 64 + ni * 16 + lr;
#pragma unroll
        for (int r = 0; r < 4; ++r) {
          float v = acc[mi][ni][r] + bias[fbase + r];
          Ob[(size_t)(fbase + r) * N_ + n] = v >= 0.f ? v : 0.01f * v;
        }
      }
    }
  } else {
    ushort_t* Ob = outb + (size_t)bp * (F_ * N_);
    float iv[4];
#pragma unroll
    for (int ni = 0; ni < 4; ++ni)
      iv[ni] = 1.0f / sumb[(size_t)bp * N_ + n0 + wn * 64 + ni * 16 + lr];
#pragma unroll
    for (int mi = 0; mi < 4; ++mi) {
      int fbase = wm * 64 + mi * 16 + quad * 4;
#pragma unroll
      for (int ni = 0; ni < 4; ++ni) {
        int n = n0 + wn * 64 + ni * 16 + lr;
#pragma unroll
        for (int r = 0; r < 4; ++r)
          Ob[(size_t)(fbase + r) * N_ + n] = f2bf(acc[mi][ni][r] * iv[ni]);
      }
    }
  }
}

// ---------------------------------------------------------------------------
extern "C" void kernel_launch(void* const* d_in, const int* in_sizes, int n_in,
                              void* d_out, int out_size, void* d_ws, size_t ws_size,
                              hipStream_t stream) {
  const float* x = (const float*)d_in[0];
  const float* mixer = (const float*)d_in[1];
  const float* weight = (const float*)d_in[2];
  const float* wb = (const float*)d_in[3];
  const float* fw = (const float*)d_in[4];
  const float* bias = (const float*)d_in[5];
  const float* S = (const float*)d_in[6];
  float* out = (float*)d_out;

  char* ws = (char*)d_ws;
  size_t off = 0;
  auto take = [&](size_t bytes) -> char* {
    char* p = ws + off;
    off = (off + bytes + 255) & ~(size_t)255;
    return p;
  };
  float* e1 = (float*)take((size_t)B_ * P_ * N_ * 4);
  float* e2 = (float*)take((size_t)B_ * P_ * N_ * 4);
  float* sumb = (float*)take((size_t)B_ * P_ * N_ * 4);
  ushort_t* fwbf = (ushort_t*)take((size_t)P_ * F_ * KHOP * G_ * 2);
  ushort_t* xT = (ushort_t*)take((size_t)B_ * N_ * G_ * 2);
  ushort_t* expT = (ushort_t*)take((size_t)B_ * P_ * N_ * N_ * 2);
  ushort_t* sA = (ushort_t*)take((size_t)B_ * P_ * F_ * N_ * 2);
  ushort_t* sB = (ushort_t*)take((size_t)B_ * P_ * F_ * N_ * 2);

  k_prep<<<1792, 256, 0, stream>>>(x, mixer, weight, wb, fw, e1, e2, fwbf, xT, sumb);
  k_att<<<dim3(4, 16, 32), 256, 0, stream>>>(e1, e2, S, expT, sumb);

  // Horner (1/rowsum folded into stored intermediates):
  // s3' = (fw3*x) . inv ; s2' = (s3'*E^T + fw2*x) . inv ;
  // s1' = (s2'*E^T + fw1*x) . inv ; out = lrelu(s1'*E^T + fw0*x + bias)
  gemm_step<<<256, 512, 0, stream>>>(nullptr, expT, fwbf, xT, bias, sumb, sA, nullptr, 3, 0, 0);
  gemm_step<<<256, 512, 0, stream>>>(sA, expT, fwbf, xT, bias, sumb, sB, nullptr, 2, 1, 0);
  gemm_step<<<256, 512, 0, stream>>>(sB, expT, fwbf, xT, bias, sumb, sA, nullptr, 1, 1, 0);
  gemm_step<<<256, 512, 0, stream>>>(sA, expT, fwbf, xT, bias, sumb, nullptr, out, 0, 1, 1);
}

// Round 4
// 273.322 us; speedup vs baseline: 1.0479x; 1.0479x over previous
//
#include <hip/hip_runtime.h>
#include <hip/hip_bf16.h>

#define B_ 8
#define G_ 256
#define N_ 1024
#define P_ 4
#define F_ 256
#define KHOP 4
#define KG_ (KHOP * G_)   // 1024

typedef unsigned short ushort_t;
typedef __bf16 bf16x8 __attribute__((ext_vector_type(8)));
typedef unsigned short u16x8 __attribute__((ext_vector_type(8)));
typedef float f32x4 __attribute__((ext_vector_type(4)));

__device__ __forceinline__ unsigned short f2bf(float f) {
  union { float fl; unsigned int i; } v; v.fl = f;
  return (unsigned short)((v.i + 0x7fffu + ((v.i >> 16) & 1u)) >> 16);
}

__device__ __forceinline__ void gload_lds16(const ushort_t* g, ushort_t* l) {
  __builtin_amdgcn_global_load_lds(
      (const __attribute__((address_space(1))) void*)g,
      (__attribute__((address_space(3))) void*)l, 16, 0, 0);
}

// ---------------------------------------------------------------------------
// K-PREP: one kernel, block-range partitioned.  (unchanged)
__global__ __launch_bounds__(256) void k_prep(
    const float* __restrict__ x, const float* __restrict__ mixer,
    const float* __restrict__ weight, const float* __restrict__ wb,
    const float* __restrict__ fw, float* __restrict__ e1, float* __restrict__ e2,
    ushort_t* __restrict__ fwbf, ushort_t* __restrict__ xT,
    float* __restrict__ sumb) {
  int blk = blockIdx.x;
  int t = threadIdx.x;
  if (blk < 128) {
    __shared__ float s1[G_], s2[G_];
    __shared__ float cred[2][4];
    int bp = blk >> 2;
    int nc = blk & 3;
    int b = bp >> 2, p = bp & (P_ - 1);
    int n = nc * 256 + t;
    float acc1 = 0.f, acc2 = 0.f;
    const float* wp = weight + (size_t)p * F_ * G_ + t;
    const float* mp = mixer + p * 2 * F_;
    for (int f = 0; f < F_; ++f) {
      float wv = wp[(size_t)f * G_];
      acc1 = fmaf(mp[f], wv, acc1);
      acc2 = fmaf(mp[F_ + f], wv, acc2);
    }
    s1[t] = acc1;
    s2[t] = acc2;
    float c1p = mp[t] * wb[p * F_ + t];
    float c2p = mp[F_ + t] * wb[p * F_ + t];
#pragma unroll
    for (int mask = 1; mask < 64; mask <<= 1) {
      c1p += __shfl_xor(c1p, mask, 64);
      c2p += __shfl_xor(c2p, mask, 64);
    }
    if ((t & 63) == 0) {
      cred[0][t >> 6] = c1p;
      cred[1][t >> 6] = c2p;
    }
    __syncthreads();
    float c1 = cred[0][0] + cred[0][1] + cred[0][2] + cred[0][3];
    float c2 = cred[1][0] + cred[1][1] + cred[1][2] + cred[1][3];
    const float* xb = x + (size_t)b * G_ * N_ + n;
    float a1 = 0.f, a2 = 0.f;
#pragma unroll 8
    for (int g = 0; g < G_; ++g) {
      float xv = xb[(size_t)g * N_];
      a1 = fmaf(s1[g], xv, a1);
      a2 = fmaf(s2[g], xv, a2);
    }
    e1[(size_t)bp * N_ + n] = c1 + a1;
    e2[(size_t)bp * N_ + n] = c2 + a2;
  } else if (blk < 128 + 1024) {
    int i = (blk - 128) * 1024 + t * 4;
    float4 v = *(const float4*)&fw[i];
    ushort4 o;
    o.x = f2bf(v.x); o.y = f2bf(v.y); o.z = f2bf(v.z); o.w = f2bf(v.w);
    *(ushort4*)&fwbf[i] = o;
  } else if (blk < 1152 + 512) {
    __shared__ ushort_t tile[64][66];
    int idx = blk - 1152;
    int n0 = (idx & 15) * 64;
    int g0 = ((idx >> 4) & 3) * 64;
    int b = idx >> 6;
    int rr = t >> 4, cc = (t & 15) * 4;
#pragma unroll
    for (int ps = 0; ps < 4; ++ps) {
      float4 v = *(const float4*)&x[((size_t)b * G_ + g0 + ps * 16 + rr) * N_ + n0 + cc];
      tile[ps * 16 + rr][cc] = f2bf(v.x);
      tile[ps * 16 + rr][cc + 1] = f2bf(v.y);
      tile[ps * 16 + rr][cc + 2] = f2bf(v.z);
      tile[ps * 16 + rr][cc + 3] = f2bf(v.w);
    }
    __syncthreads();
#pragma unroll
    for (int ps = 0; ps < 4; ++ps) {
      int nl = ps * 16 + rr;
      int gl = cc;
      ushort4 o;
      o.x = tile[gl][nl];
      o.y = tile[gl + 1][nl];
      o.z = tile[gl + 2][nl];
      o.w = tile[gl + 3][nl];
      *(ushort4*)&xT[((size_t)b * N_ + n0 + nl) * G_ + g0 + gl] = o;
    }
  } else {
    int i = (blk - 1664) * 256 + t;
    sumb[i] = 0.f;
  }
}

// ---------------------------------------------------------------------------
// K5: attention, UNNORMALIZED.  (unchanged)
__global__ __launch_bounds__(256) void k_att(const float* __restrict__ e1,
                                             const float* __restrict__ e2,
                                             const float* __restrict__ S,
                                             ushort_t* __restrict__ expT,
                                             float* __restrict__ sumb) {
  __shared__ ushort_t tile[256][72];   // [j-local][i-local]
  __shared__ float se1[256];
  __shared__ float se2[64];
  int bp = blockIdx.z;
  int b = bp >> 2;
  int i0 = blockIdx.y * 64;
  int jt = blockIdx.x;
  int j0 = jt * 256;
  int t = threadIdx.x;
  int rr = t >> 4;
  int cc4 = t & 15;
  int cc = cc4 * 4;

  se1[t] = e1[(size_t)bp * N_ + j0 + t];
  if (t < 64) se2[t] = e2[(size_t)bp * N_ + i0 + t];
  __syncthreads();

  const float* Sb = S + (size_t)b * N_ * N_;
  float re2[4];
#pragma unroll
  for (int ps = 0; ps < 4; ++ps) re2[ps] = se2[ps * 16 + rr];
  float psum[4] = {0.f, 0.f, 0.f, 0.f};
#pragma unroll
  for (int js = 0; js < 4; ++js) {
    float4 e1q = *(float4*)&se1[js * 64 + cc];
    float e1v[4] = {e1q.x, e1q.y, e1q.z, e1q.w};
#pragma unroll
    for (int ps = 0; ps < 4; ++ps) {
      int il = ps * 16 + rr;
      float4 s4 = *(const float4*)&Sb[(size_t)(i0 + il) * N_ + j0 + js * 64 + cc];
      float sv[4] = {s4.x, s4.y, s4.z, s4.w};
#pragma unroll
      for (int s = 0; s < 4; ++s) {
        float v = e1v[s] + re2[ps];
        float l = v >= 0.f ? v : 0.2f * v;
        bool m = fabsf(sv[s]) > 1e-9f;
        float e = m ? __expf(l) : 0.f;
        psum[ps] += e;
        tile[js * 64 + cc + s][il] = f2bf(e);
      }
    }
  }
#pragma unroll
  for (int mask = 1; mask < 16; mask <<= 1) {
#pragma unroll
    for (int ps = 0; ps < 4; ++ps) psum[ps] += __shfl_xor(psum[ps], mask, 64);
  }
  if (cc4 == 0) {
#pragma unroll
    for (int ps = 0; ps < 4; ++ps)
      atomicAdd(&sumb[(size_t)bp * N_ + i0 + ps * 16 + rr], psum[ps]);
  }
  __syncthreads();
  ushort_t* Tb = expT + (size_t)bp * N_ * N_;
  int jl0 = t >> 3;         // 0..31
  int ig = (t & 7) * 8;     // 0..56
#pragma unroll
  for (int pass = 0; pass < 8; ++pass) {
    int jl = pass * 32 + jl0;
    u16x8 v = *(const u16x8*)&tile[jl][ig];
    *(u16x8*)&Tb[(size_t)(j0 + jl) * N_ + i0 + ig] = v;
  }
}

// ---------------------------------------------------------------------------
// K6 v5: = v2 pipeline (128x128 tile, 4 waves 2x2, BK=64, dbuf, depth-1
// prefetch with counted vmcnt(8), 2 blocks/CU) + v4's PROVEN frag-major
// LDS layout (zero bank conflicts).
//
// Frag-major: tile element (row,k), row<128, k<64, lives at flat ushort
//   offset cell*512 + lane*8 + e, where cell = (row>>4)*2 + (k>>5),
//   lane = ((k>>3)&3)*16 + (row&15), e = k&7.  Each 16x32 MFMA fragment
//   is a contiguous 1 KB block in exact lane order -> every ds_read_b128
//   is a wave-contiguous 1 KB read (no conflicts).  Achieved with LINEAR
//   global_load_lds destinations + permuted per-lane global sources
//   (rule 21): global segments stay 64 B-contiguous (4 quads cover
//   k 0..31 of each row).
__global__ __launch_bounds__(256, 2) void gemm_step(
    const ushort_t* __restrict__ Aprev, const ushort_t* __restrict__ Bt,
    const ushort_t* __restrict__ fwbf, const ushort_t* __restrict__ xT,
    const float* __restrict__ bias, const float* __restrict__ sumb,
    ushort_t* __restrict__ outb, float* __restrict__ outf,
    int kslice, int has_prev, int last) {
  __shared__ ushort_t As[2][8192];   // 16 KB per buf: 16 cells x 1 KB
  __shared__ ushort_t Bs[2][8192];
  // ---- XCD-aware decode: id&7 = xcd, 4 bps per XCD, 16 blocks per bp ----
  int id = blockIdx.x;
  int xcd = id & 7;
  int slot = id >> 3;            // 0..63
  int bp = xcd * 4 + (slot >> 4);
  int inner = slot & 15;
  int m0 = (inner >> 3) * 128;   // 0..128
  int n0 = (inner & 7) * 128;    // 0..896
  int p = bp & (P_ - 1), b = bp >> 2;
  int t = threadIdx.x;
  int lane = t & 63;
  int w = t >> 6;                // 0..3
  int wm = w >> 1, wn = w & 1;   // 2x2 wave grid, wave tile 64x64
  int lr = lane & 15, quad = lane >> 4;

  // staging coordinates: wave w stages cells {w, w+4, w+8, w+12}
  int rowF[4], colF[4];
#pragma unroll
  for (int l = 0; l < 4; ++l) {
    int cell = l * 4 + w;                 // 0..15
    rowF[l] = (cell >> 1) * 16 + lr;      // 0..127
    colF[l] = (cell & 1) * 32 + quad * 8; // 0..56
  }

  const ushort_t* Abase1 = has_prev ? (Aprev + (size_t)bp * (F_ * N_)) : fwbf;
  const ushort_t* Abase2 = fwbf + (size_t)p * (F_ * KG_) + (size_t)kslice * G_;
  const ushort_t* Bbase1 = Bt + (size_t)bp * N_ * N_;
  const ushort_t* Bbase2 = xT + (size_t)b * (N_ * G_);

  const ushort_t *pA1[4], *pA2[4], *pB1[4], *pB2[4];
#pragma unroll
  for (int l = 0; l < 4; ++l) {
    pA1[l] = Abase1 + (size_t)(m0 + rowF[l]) * N_ + colF[l];
    pA2[l] = Abase2 + (size_t)(m0 + rowF[l]) * KG_ + colF[l];
    pB1[l] = Bbase1 + (size_t)(n0 + rowF[l]) * N_ + colF[l];
    pB2[l] = Bbase2 + (size_t)(n0 + rowF[l]) * G_ + colF[l];
  }

  const int ntA = has_prev ? (N_ / 64) : 0;   // 16 or 0
  const int NT = ntA + G_ / 64;               // 20 or 4

  f32x4 acc[4][4] = {};

  auto stage = [&](int it, int buf) {
    if (it < ntA) {
      int ko = it * 64;
#pragma unroll
      for (int l = 0; l < 4; ++l)
        gload_lds16(pA1[l] + ko, &As[buf][(l * 4 + w) * 512]);
#pragma unroll
      for (int l = 0; l < 4; ++l)
        gload_lds16(pB1[l] + ko, &Bs[buf][(l * 4 + w) * 512]);
    } else {
      int ko = (it - ntA) * 64;
#pragma unroll
      for (int l = 0; l < 4; ++l)
        gload_lds16(pA2[l] + ko, &As[buf][(l * 4 + w) * 512]);
#pragma unroll
      for (int l = 0; l < 4; ++l)
        gload_lds16(pB2[l] + ko, &Bs[buf][(l * 4 + w) * 512]);
    }
  };

  // prologue: stage tile 0 into buf 0 (8 loads/wave in flight)
  stage(0, 0);
  int cur = 0;
  for (int it = 0; it < NT; ++it) {
    if (it + 1 < NT) {
      stage(it + 1, cur ^ 1);                          // 16 in flight
      asm volatile("s_waitcnt vmcnt(8)" ::: "memory"); // cur tile landed
    } else {
      asm volatile("s_waitcnt vmcnt(0)" ::: "memory");
    }
    __builtin_amdgcn_s_barrier();        // all waves' cur-tile DMA visible
#pragma unroll
    for (int c = 0; c < 2; ++c) {
      bf16x8 af[4], bfr[4];
#pragma unroll
      for (int mi = 0; mi < 4; ++mi)
        af[mi] = __builtin_bit_cast(bf16x8,
            *(const u16x8*)&As[cur][(((wm * 4 + mi) * 2) + c) * 512 + lane * 8]);
#pragma unroll
      for (int ni = 0; ni < 4; ++ni)
        bfr[ni] = __builtin_bit_cast(bf16x8,
            *(const u16x8*)&Bs[cur][(((wn * 4 + ni) * 2) + c) * 512 + lane * 8]);
#pragma unroll
      for (int mi = 0; mi < 4; ++mi)
#pragma unroll
        for (int ni = 0; ni < 4; ++ni)
          acc[mi][ni] = __builtin_amdgcn_mfma_f32_16x16x32_bf16(af[mi], bfr[ni], acc[mi][ni], 0, 0, 0);
    }
    __builtin_amdgcn_s_barrier();        // reads done before buf overwritten
    cur ^= 1;
  }

  if (last) {
    float* Ob = outf + (size_t)bp * (F_ * N_);
#pragma unroll
    for (int mi = 0; mi < 4; ++mi) {
      int fbase = m0 + wm * 64 + mi * 16 + quad * 4;
#pragma unroll
      for (int ni = 0; ni < 4; ++ni) {
        int n = n0 + wn * 64 + ni * 16 + lr;
#pragma unroll
        for (int r = 0; r < 4; ++r) {
          float v = acc[mi][ni][r] + bias[fbase + r];
          Ob[(size_t)(fbase + r) * N_ + n] = v >= 0.f ? v : 0.01f * v;
        }
      }
    }
  } else {
    ushort_t* Ob = outb + (size_t)bp * (F_ * N_);
    float iv[4];
#pragma unroll
    for (int ni = 0; ni < 4; ++ni)
      iv[ni] = 1.0f / sumb[(size_t)bp * N_ + n0 + wn * 64 + ni * 16 + lr];
#pragma unroll
    for (int mi = 0; mi < 4; ++mi) {
      int fbase = m0 + wm * 64 + mi * 16 + quad * 4;
#pragma unroll
      for (int ni = 0; ni < 4; ++ni) {
        int n = n0 + wn * 64 + ni * 16 + lr;
#pragma unroll
        for (int r = 0; r < 4; ++r)
          Ob[(size_t)(fbase + r) * N_ + n] = f2bf(acc[mi][ni][r] * iv[ni]);
      }
    }
  }
}

// ---------------------------------------------------------------------------
extern "C" void kernel_launch(void* const* d_in, const int* in_sizes, int n_in,
                              void* d_out, int out_size, void* d_ws, size_t ws_size,
                              hipStream_t stream) {
  const float* x = (const float*)d_in[0];
  const float* mixer = (const float*)d_in[1];
  const float* weight = (const float*)d_in[2];
  const float* wb = (const float*)d_in[3];
  const float* fw = (const float*)d_in[4];
  const float* bias = (const float*)d_in[5];
  const float* S = (const float*)d_in[6];
  float* out = (float*)d_out;

  char* ws = (char*)d_ws;
  size_t off = 0;
  auto take = [&](size_t bytes) -> char* {
    char* p = ws + off;
    off = (off + bytes + 255) & ~(size_t)255;
    return p;
  };
  float* e1 = (float*)take((size_t)B_ * P_ * N_ * 4);
  float* e2 = (float*)take((size_t)B_ * P_ * N_ * 4);
  float* sumb = (float*)take((size_t)B_ * P_ * N_ * 4);
  ushort_t* fwbf = (ushort_t*)take((size_t)P_ * F_ * KHOP * G_ * 2);
  ushort_t* xT = (ushort_t*)take((size_t)B_ * N_ * G_ * 2);
  ushort_t* expT = (ushort_t*)take((size_t)B_ * P_ * N_ * N_ * 2);
  ushort_t* sA = (ushort_t*)take((size_t)B_ * P_ * F_ * N_ * 2);
  ushort_t* sB = (ushort_t*)take((size_t)B_ * P_ * F_ * N_ * 2);

  k_prep<<<1792, 256, 0, stream>>>(x, mixer, weight, wb, fw, e1, e2, fwbf, xT, sumb);
  k_att<<<dim3(4, 16, 32), 256, 0, stream>>>(e1, e2, S, expT, sumb);

  // Horner (1/rowsum folded into stored intermediates):
  // s3' = (fw3*x) . inv ; s2' = (s3'*E^T + fw2*x) . inv ;
  // s1' = (s2'*E^T + fw1*x) . inv ; out = lrelu(s1'*E^T + fw0*x + bias)
  gemm_step<<<512, 256, 0, stream>>>(nullptr, expT, fwbf, xT, bias, sumb, sA, nullptr, 3, 0, 0);
  gemm_step<<<512, 256, 0, stream>>>(sA, expT, fwbf, xT, bias, sumb, sB, nullptr, 2, 1, 0);
  gemm_step<<<512, 256, 0, stream>>>(sB, expT, fwbf, xT, bias, sumb, sA, nullptr, 1, 1, 0);
  gemm_step<<<512, 256, 0, stream>>>(sA, expT, fwbf, xT, bias, sumb, nullptr, out, 0, 1, 1);
}

// Round 5
// 226.941 us; speedup vs baseline: 1.2620x; 1.2044x over previous
//
#include <hip/hip_runtime.h>
#include <hip/hip_bf16.h>

#define B_ 8
#define G_ 256
#define N_ 1024
#define P_ 4
#define F_ 256
#define KHOP 4
#define KG_ (KHOP * G_)   // 1024

// ---------------------------------------------------------------------------
// GLOBAL TILED LAYOUT (shared by expT, fwbf, xT, sA/sB):
//   matrix [R rows][C k-cols] -> tiles [R/128][C/64], each tile 8192 ushorts
//   (16 KB) contiguous.  Within a tile, element (r,k), r<128, k<64:
//     cell = (r>>4)*2 + (k>>5)            [0..15]
//     lane = ((k>>3)&3)*16 + (r&15)       [0..63]
//     e    = k&7
//     flat = cell*512 + lane*8 + e
//   This is exactly the MFMA A/B fragment order: one cell = one 16x32
//   fragment, lane-ordered.  Staging a tile = 16 contiguous 1 KB reads.
// ---------------------------------------------------------------------------

typedef unsigned short ushort_t;
typedef __bf16 bf16x8 __attribute__((ext_vector_type(8)));
typedef unsigned short u16x8 __attribute__((ext_vector_type(8)));
typedef float f32x4 __attribute__((ext_vector_type(4)));

__device__ __forceinline__ unsigned short f2bf(float f) {
  union { float fl; unsigned int i; } v; v.fl = f;
  return (unsigned short)((v.i + 0x7fffu + ((v.i >> 16) & 1u)) >> 16);
}

__device__ __forceinline__ void gload_lds16(const ushort_t* g, ushort_t* l) {
  __builtin_amdgcn_global_load_lds(
      (const __attribute__((address_space(1))) void*)g,
      (__attribute__((address_space(3))) void*)l, 16, 0, 0);
}

// ---------------------------------------------------------------------------
// K-PREP: block ranges: [0,128) e1/e2 | [128,256) fwbf tiled cast |
// [256,768) xT transpose+tiled | [768,896) zero sumb.
__global__ __launch_bounds__(256) void k_prep(
    const float* __restrict__ x, const float* __restrict__ mixer,
    const float* __restrict__ weight, const float* __restrict__ wb,
    const float* __restrict__ fw, float* __restrict__ e1, float* __restrict__ e2,
    ushort_t* __restrict__ fwbf, ushort_t* __restrict__ xT,
    float* __restrict__ sumb) {
  int blk = blockIdx.x;
  int t = threadIdx.x;
  if (blk < 128) {
    __shared__ float s1[G_], s2[G_];
    __shared__ float cred[2][4];
    int bp = blk >> 2;
    int nc = blk & 3;
    int b = bp >> 2, p = bp & (P_ - 1);
    int n = nc * 256 + t;
    float acc1 = 0.f, acc2 = 0.f;
    const float* wp = weight + (size_t)p * F_ * G_ + t;
    const float* mp = mixer + p * 2 * F_;
    for (int f = 0; f < F_; ++f) {
      float wv = wp[(size_t)f * G_];
      acc1 = fmaf(mp[f], wv, acc1);
      acc2 = fmaf(mp[F_ + f], wv, acc2);
    }
    s1[t] = acc1;
    s2[t] = acc2;
    float c1p = mp[t] * wb[p * F_ + t];
    float c2p = mp[F_ + t] * wb[p * F_ + t];
#pragma unroll
    for (int mask = 1; mask < 64; mask <<= 1) {
      c1p += __shfl_xor(c1p, mask, 64);
      c2p += __shfl_xor(c2p, mask, 64);
    }
    if ((t & 63) == 0) {
      cred[0][t >> 6] = c1p;
      cred[1][t >> 6] = c2p;
    }
    __syncthreads();
    float c1 = cred[0][0] + cred[0][1] + cred[0][2] + cred[0][3];
    float c2 = cred[1][0] + cred[1][1] + cred[1][2] + cred[1][3];
    const float* xb = x + (size_t)b * G_ * N_ + n;
    float a1 = 0.f, a2 = 0.f;
#pragma unroll 8
    for (int g = 0; g < G_; ++g) {
      float xv = xb[(size_t)g * N_];
      a1 = fmaf(s1[g], xv, a1);
      a2 = fmaf(s2[g], xv, a2);
    }
    e1[(size_t)bp * N_ + n] = c1 + a1;
    e2[(size_t)bp * N_ + n] = c2 + a2;
  } else if (blk < 256) {
    // ---- fwbf cast, tiled: one block per tile (p, mb, kb) ----
    int tile = blk - 128;            // 0..127
    int p = tile >> 5;
    int mb = (tile >> 4) & 1;
    int kb = tile & 15;
    int w = t >> 6, lane = t & 63;
    size_t tbase = ((size_t)(p * 2 + mb) * 16 + kb) * 8192;
#pragma unroll
    for (int q = 0; q < 4; ++q) {
      int cell = q * 4 + w;
      int f = mb * 128 + (cell >> 1) * 16 + (lane & 15);
      int kg = kb * 64 + (cell & 1) * 32 + (lane >> 4) * 8;
      const float* s = fw + ((size_t)p * F_ + f) * KG_ + kg;
      float4 v0 = *(const float4*)&s[0];
      float4 v1 = *(const float4*)&s[4];
      u16x8 o;
      o[0] = f2bf(v0.x); o[1] = f2bf(v0.y); o[2] = f2bf(v0.z); o[3] = f2bf(v0.w);
      o[4] = f2bf(v1.x); o[5] = f2bf(v1.y); o[6] = f2bf(v1.z); o[7] = f2bf(v1.w);
      *(u16x8*)&fwbf[tbase + (size_t)cell * 512 + lane * 8] = o;
    }
  } else if (blk < 768) {
    // ---- xT transpose+cast, tiled output ----
    __shared__ ushort_t tile[64][66];
    int idx = blk - 256;
    int n0 = (idx & 15) * 64;
    int g0 = ((idx >> 4) & 3) * 64;
    int b = idx >> 6;
    int rr = t >> 4, cc = (t & 15) * 4;
#pragma unroll
    for (int ps = 0; ps < 4; ++ps) {
      float4 v = *(const float4*)&x[((size_t)b * G_ + g0 + ps * 16 + rr) * N_ + n0 + cc];
      tile[ps * 16 + rr][cc] = f2bf(v.x);
      tile[ps * 16 + rr][cc + 1] = f2bf(v.y);
      tile[ps * 16 + rr][cc + 2] = f2bf(v.z);
      tile[ps * 16 + rr][cc + 3] = f2bf(v.w);
    }
    __syncthreads();
    int w = t >> 6, lane = t & 63;
    int nb = n0 >> 7;                 // 0..7
    int kb = g0 >> 6;                 // 0..3
    int rhalf = (n0 & 64) >> 4;       // 0 or 4
    size_t tbase = ((size_t)(b * 8 + nb) * 4 + kb) * 8192;
#pragma unroll
    for (int q = 0; q < 2; ++q) {
      int cl = q * 4 + w;                         // 0..7 local cell
      int cell = (rhalf + (cl >> 1)) * 2 + (cl & 1);
      int nl = (cl >> 1) * 16 + (lane & 15);      // 0..63 local n
      int gl = (cl & 1) * 32 + (lane >> 4) * 8;   // 0..56
      u16x8 v;
#pragma unroll
      for (int j = 0; j < 8; ++j) v[j] = tile[gl + j][nl];
      *(u16x8*)&xT[tbase + (size_t)cell * 512 + lane * 8] = v;
    }
  } else {
    int i = (blk - 768) * 256 + t;
    sumb[i] = 0.f;
  }
}

// ---------------------------------------------------------------------------
// K5: attention, UNNORMALIZED.  Dump now writes the tiled layout with
// wave-contiguous 1 KB stores.
__global__ __launch_bounds__(256) void k_att(const float* __restrict__ e1,
                                             const float* __restrict__ e2,
                                             const float* __restrict__ S,
                                             ushort_t* __restrict__ expT,
                                             float* __restrict__ sumb) {
  __shared__ ushort_t tile[256][72];   // [j-local][i-local]
  __shared__ float se1[256];
  __shared__ float se2[64];
  int bp = blockIdx.z;
  int b = bp >> 2;
  int i0 = blockIdx.y * 64;   // k-dim chunk
  int jt = blockIdx.x;
  int j0 = jt * 256;          // n-dim chunk
  int t = threadIdx.x;
  int rr = t >> 4;
  int cc4 = t & 15;
  int cc = cc4 * 4;

  se1[t] = e1[(size_t)bp * N_ + j0 + t];
  if (t < 64) se2[t] = e2[(size_t)bp * N_ + i0 + t];
  __syncthreads();

  const float* Sb = S + (size_t)b * N_ * N_;
  float re2[4];
#pragma unroll
  for (int ps = 0; ps < 4; ++ps) re2[ps] = se2[ps * 16 + rr];
  float psum[4] = {0.f, 0.f, 0.f, 0.f};
#pragma unroll
  for (int js = 0; js < 4; ++js) {
    float4 e1q = *(float4*)&se1[js * 64 + cc];
    float e1v[4] = {e1q.x, e1q.y, e1q.z, e1q.w};
#pragma unroll
    for (int ps = 0; ps < 4; ++ps) {
      int il = ps * 16 + rr;
      float4 s4 = *(const float4*)&Sb[(size_t)(i0 + il) * N_ + j0 + js * 64 + cc];
      float sv[4] = {s4.x, s4.y, s4.z, s4.w};
#pragma unroll
      for (int s = 0; s < 4; ++s) {
        float v = e1v[s] + re2[ps];
        float l = v >= 0.f ? v : 0.2f * v;
        bool m = fabsf(sv[s]) > 1e-9f;
        float e = m ? __expf(l) : 0.f;
        psum[ps] += e;
        tile[js * 64 + cc + s][il] = f2bf(e);
      }
    }
  }
#pragma unroll
  for (int mask = 1; mask < 16; mask <<= 1) {
#pragma unroll
    for (int ps = 0; ps < 4; ++ps) psum[ps] += __shfl_xor(psum[ps], mask, 64);
  }
  if (cc4 == 0) {
#pragma unroll
    for (int ps = 0; ps < 4; ++ps)
      atomicAdd(&sumb[(size_t)bp * N_ + i0 + ps * 16 + rr], psum[ps]);
  }
  __syncthreads();
  // dump: tiled layout, wave-contiguous 1 KB global stores
  int w = t >> 6, lane = t & 63;
  int kb = i0 >> 6;
#pragma unroll
  for (int hb = 0; hb < 2; ++hb) {
    size_t tbase = ((size_t)(bp * 8 + (j0 >> 7) + hb) * 16 + kb) * 8192;
#pragma unroll
    for (int q = 0; q < 4; ++q) {
      int cell = q * 4 + w;
      int r = (cell >> 1) * 16 + (lane & 15);
      int il = (cell & 1) * 32 + (lane >> 4) * 8;
      u16x8 v = *(const u16x8*)&tile[hb * 128 + r][il];
      *(u16x8*)&expT[tbase + (size_t)cell * 512 + lane * 8] = v;
    }
  }
}

// ---------------------------------------------------------------------------
// K6 v6: 128x128 tile, 4 waves 2x2, BK=64, dbuf, counted vmcnt(8), 2
// blocks/CU -- plus ALL operands in the global tiled layout: every
// global_load_lds reads a contiguous 1 KB cell (8 full 128 B lines).
// Epilogue (non-last) writes C through LDS scratch back in tiled layout
// with wave-contiguous 1 KB stores.
__global__ __launch_bounds__(256, 2) void gemm_step(
    const ushort_t* __restrict__ Aprev, const ushort_t* __restrict__ Bt,
    const ushort_t* __restrict__ fwbf, const ushort_t* __restrict__ xT,
    const float* __restrict__ bias, const float* __restrict__ sumb,
    ushort_t* __restrict__ outb, float* __restrict__ outf,
    int kslice, int has_prev, int last) {
  __shared__ ushort_t As[2][8192];   // 16 KB per buf: 16 cells x 1 KB
  __shared__ ushort_t Bs[2][8192];
  // ---- XCD-aware decode: id&7 = xcd, 4 bps per XCD, 16 blocks per bp ----
  int id = blockIdx.x;
  int xcd = id & 7;
  int slot = id >> 3;            // 0..63
  int bp = xcd * 4 + (slot >> 4);
  int inner = slot & 15;
  int mb = inner >> 3;           // 0..1
  int m0 = mb * 128;
  int nb = inner & 7;            // 0..7
  int n0 = nb * 128;
  int p = bp & (P_ - 1), b = bp >> 2;
  int t = threadIdx.x;
  int lane = t & 63;
  int w = t >> 6;                // 0..3
  int wm = w >> 1, wn = w & 1;   // 2x2 wave grid, wave tile 64x64
  int lr = lane & 15, quad = lane >> 4;

  // tiled bases (ushort offsets); per k-step add it*8192
  const ushort_t* A1 = has_prev ? (Aprev + (size_t)(bp * 2 + mb) * 16 * 8192) : fwbf;
  const ushort_t* A2 = fwbf + ((size_t)(p * 2 + mb) * 16 + kslice * 4) * 8192;
  const ushort_t* B1 = Bt + (size_t)(bp * 8 + nb) * 16 * 8192;
  const ushort_t* B2 = xT + (size_t)(b * 8 + nb) * 4 * 8192;

  const int ntA = has_prev ? (N_ / 64) : 0;   // 16 or 0
  const int NT = ntA + G_ / 64;               // 20 or 4

  f32x4 acc[4][4] = {};

  int laneoff = lane * 8;
  auto stage = [&](int it, int buf) {
    const ushort_t *Ab, *Bb;
    if (it < ntA) {
      Ab = A1 + (size_t)it * 8192;
      Bb = B1 + (size_t)it * 8192;
    } else {
      Ab = A2 + (size_t)(it - ntA) * 8192;
      Bb = B2 + (size_t)(it - ntA) * 8192;
    }
#pragma unroll
    for (int l = 0; l < 4; ++l) {
      int coff = (w * 4 + l) * 512;
      gload_lds16(Ab + coff + laneoff, &As[buf][coff]);
      gload_lds16(Bb + coff + laneoff, &Bs[buf][coff]);
    }
  };

  // prologue: stage tile 0 into buf 0 (8 loads/wave in flight)
  stage(0, 0);
  int cur = 0;
  for (int it = 0; it < NT; ++it) {
    if (it + 1 < NT) {
      stage(it + 1, cur ^ 1);                          // 16 in flight
      asm volatile("s_waitcnt vmcnt(8)" ::: "memory"); // cur tile landed
    } else {
      asm volatile("s_waitcnt vmcnt(0)" ::: "memory");
    }
    __builtin_amdgcn_s_barrier();        // all waves' cur-tile DMA visible
#pragma unroll
    for (int c = 0; c < 2; ++c) {
      bf16x8 af[4], bfr[4];
#pragma unroll
      for (int mi = 0; mi < 4; ++mi)
        af[mi] = __builtin_bit_cast(bf16x8,
            *(const u16x8*)&As[cur][(((wm * 4 + mi) * 2) + c) * 512 + lane * 8]);
#pragma unroll
      for (int ni = 0; ni < 4; ++ni)
        bfr[ni] = __builtin_bit_cast(bf16x8,
            *(const u16x8*)&Bs[cur][(((wn * 4 + ni) * 2) + c) * 512 + lane * 8]);
#pragma unroll
      for (int mi = 0; mi < 4; ++mi)
#pragma unroll
        for (int ni = 0; ni < 4; ++ni)
          acc[mi][ni] = __builtin_amdgcn_mfma_f32_16x16x32_bf16(af[mi], bfr[ni], acc[mi][ni], 0, 0, 0);
    }
    __builtin_amdgcn_s_barrier();        // reads done before buf overwritten
    cur ^= 1;
  }

  if (last) {
    float* Ob = outf + (size_t)bp * (F_ * N_);
#pragma unroll
    for (int mi = 0; mi < 4; ++mi) {
      int fbase = m0 + wm * 64 + mi * 16 + quad * 4;
#pragma unroll
      for (int ni = 0; ni < 4; ++ni) {
        int n = n0 + wn * 64 + ni * 16 + lr;
#pragma unroll
        for (int r = 0; r < 4; ++r) {
          float v = acc[mi][ni][r] + bias[fbase + r];
          Ob[(size_t)(fbase + r) * N_ + n] = v >= 0.f ? v : 0.01f * v;
        }
      }
    }
  } else {
    // epilogue via LDS scratch -> tiled global layout (next step's A)
    ushort_t* scratch = &As[0][0];   // 16384 ushorts = 32 KB
    float iv[4];
#pragma unroll
    for (int ni = 0; ni < 4; ++ni)
      iv[ni] = 1.0f / sumb[(size_t)bp * N_ + n0 + wn * 64 + ni * 16 + lr];
#pragma unroll
    for (int mi = 0; mi < 4; ++mi) {
#pragma unroll
      for (int ni = 0; ni < 4; ++ni) {
        int nL = wn * 64 + ni * 16 + lr;          // block-local n (= k of next A)
        int kbh = nL >> 6;                        // 0 or 1
        int kloc = nL & 63;
        int cellbase = kbh * 8192 +
                       ((wm * 4 + mi) * 2 + (kloc >> 5)) * 512 +
                       (((kloc >> 3) & 3) * 16 + quad * 4) * 8 + (kloc & 7);
#pragma unroll
        for (int r = 0; r < 4; ++r)
          scratch[cellbase + r * 8] = f2bf(acc[mi][ni][r] * iv[ni]);
      }
    }
    __syncthreads();
    size_t obase = ((size_t)(bp * 2 + mb) * 16 + (n0 >> 6)) * 8192;
#pragma unroll
    for (int pass = 0; pass < 8; ++pass) {
      int fl = pass * 2048 + t * 8;
      *(u16x8*)&outb[obase + fl] = *(const u16x8*)&scratch[fl];
    }
  }
}

// ---------------------------------------------------------------------------
extern "C" void kernel_launch(void* const* d_in, const int* in_sizes, int n_in,
                              void* d_out, int out_size, void* d_ws, size_t ws_size,
                              hipStream_t stream) {
  const float* x = (const float*)d_in[0];
  const float* mixer = (const float*)d_in[1];
  const float* weight = (const float*)d_in[2];
  const float* wb = (const float*)d_in[3];
  const float* fw = (const float*)d_in[4];
  const float* bias = (const float*)d_in[5];
  const float* S = (const float*)d_in[6];
  float* out = (float*)d_out;

  char* ws = (char*)d_ws;
  size_t off = 0;
  auto take = [&](size_t bytes) -> char* {
    char* p = ws + off;
    off = (off + bytes + 255) & ~(size_t)255;
    return p;
  };
  float* e1 = (float*)take((size_t)B_ * P_ * N_ * 4);
  float* e2 = (float*)take((size_t)B_ * P_ * N_ * 4);
  float* sumb = (float*)take((size_t)B_ * P_ * N_ * 4);
  ushort_t* fwbf = (ushort_t*)take((size_t)P_ * F_ * KHOP * G_ * 2);
  ushort_t* xT = (ushort_t*)take((size_t)B_ * N_ * G_ * 2);
  ushort_t* expT = (ushort_t*)take((size_t)B_ * P_ * N_ * N_ * 2);
  ushort_t* sA = (ushort_t*)take((size_t)B_ * P_ * F_ * N_ * 2);
  ushort_t* sB = (ushort_t*)take((size_t)B_ * P_ * F_ * N_ * 2);

  k_prep<<<896, 256, 0, stream>>>(x, mixer, weight, wb, fw, e1, e2, fwbf, xT, sumb);
  k_att<<<dim3(4, 16, 32), 256, 0, stream>>>(e1, e2, S, expT, sumb);

  // Horner (1/rowsum folded into stored intermediates):
  // s3' = (fw3*x) . inv ; s2' = (s3'*E^T + fw2*x) . inv ;
  // s1' = (s2'*E^T + fw1*x) . inv ; out = lrelu(s1'*E^T + fw0*x + bias)
  gemm_step<<<512, 256, 0, stream>>>(nullptr, expT, fwbf, xT, bias, sumb, sA, nullptr, 3, 0, 0);
  gemm_step<<<512, 256, 0, stream>>>(sA, expT, fwbf, xT, bias, sumb, sB, nullptr, 2, 1, 0);
  gemm_step<<<512, 256, 0, stream>>>(sB, expT, fwbf, xT, bias, sumb, sA, nullptr, 1, 1, 0);
  gemm_step<<<512, 256, 0, stream>>>(sA, expT, fwbf, xT, bias, sumb, nullptr, out, 0, 1, 1);
}

// Round 6
// 226.842 us; speedup vs baseline: 1.2626x; 1.0004x over previous
//
#include <hip/hip_runtime.h>
#include <hip/hip_bf16.h>

#define B_ 8
#define G_ 256
#define N_ 1024
#define P_ 4
#define F_ 256
#define KHOP 4
#define KG_ (KHOP * G_)   // 1024

// ---------------------------------------------------------------------------
// GLOBAL TILED LAYOUT (shared by expT, fwbf, xT, sA/sB):
//   matrix [R rows][C k-cols] -> tiles [R/128][C/64], each tile 8192 ushorts
//   (16 KB) contiguous.  Within a tile, element (r,k), r<128, k<64:
//     cell = (r>>4)*2 + (k>>5)            [0..15]
//     lane = ((k>>3)&3)*16 + (r&15)       [0..63]
//     e    = k&7
//     flat = cell*512 + lane*8 + e
//   One cell = one 16x32 MFMA fragment in exact lane order.
//   Staging a tile = 16 contiguous 1 KB reads (8 full 128 B lines each).
// ---------------------------------------------------------------------------

typedef unsigned short ushort_t;
typedef __bf16 bf16x8 __attribute__((ext_vector_type(8)));
typedef unsigned short u16x8 __attribute__((ext_vector_type(8)));
typedef float f32x4 __attribute__((ext_vector_type(4)));

__device__ __forceinline__ unsigned short f2bf(float f) {
  union { float fl; unsigned int i; } v; v.fl = f;
  return (unsigned short)((v.i + 0x7fffu + ((v.i >> 16) & 1u)) >> 16);
}

__device__ __forceinline__ void gload_lds16(const ushort_t* g, ushort_t* l) {
  __builtin_amdgcn_global_load_lds(
      (const __attribute__((address_space(1))) void*)g,
      (__attribute__((address_space(3))) void*)l, 16, 0, 0);
}

// ---------------------------------------------------------------------------
// K-PREP: block ranges: [0,128) e1/e2 | [128,256) fwbf tiled cast |
// [256,768) xT transpose+tiled | [768,896) zero sumb.   (unchanged)
__global__ __launch_bounds__(256) void k_prep(
    const float* __restrict__ x, const float* __restrict__ mixer,
    const float* __restrict__ weight, const float* __restrict__ wb,
    const float* __restrict__ fw, float* __restrict__ e1, float* __restrict__ e2,
    ushort_t* __restrict__ fwbf, ushort_t* __restrict__ xT,
    float* __restrict__ sumb) {
  int blk = blockIdx.x;
  int t = threadIdx.x;
  if (blk < 128) {
    __shared__ float s1[G_], s2[G_];
    __shared__ float cred[2][4];
    int bp = blk >> 2;
    int nc = blk & 3;
    int b = bp >> 2, p = bp & (P_ - 1);
    int n = nc * 256 + t;
    float acc1 = 0.f, acc2 = 0.f;
    const float* wp = weight + (size_t)p * F_ * G_ + t;
    const float* mp = mixer + p * 2 * F_;
    for (int f = 0; f < F_; ++f) {
      float wv = wp[(size_t)f * G_];
      acc1 = fmaf(mp[f], wv, acc1);
      acc2 = fmaf(mp[F_ + f], wv, acc2);
    }
    s1[t] = acc1;
    s2[t] = acc2;
    float c1p = mp[t] * wb[p * F_ + t];
    float c2p = mp[F_ + t] * wb[p * F_ + t];
#pragma unroll
    for (int mask = 1; mask < 64; mask <<= 1) {
      c1p += __shfl_xor(c1p, mask, 64);
      c2p += __shfl_xor(c2p, mask, 64);
    }
    if ((t & 63) == 0) {
      cred[0][t >> 6] = c1p;
      cred[1][t >> 6] = c2p;
    }
    __syncthreads();
    float c1 = cred[0][0] + cred[0][1] + cred[0][2] + cred[0][3];
    float c2 = cred[1][0] + cred[1][1] + cred[1][2] + cred[1][3];
    const float* xb = x + (size_t)b * G_ * N_ + n;
    float a1 = 0.f, a2 = 0.f;
#pragma unroll 8
    for (int g = 0; g < G_; ++g) {
      float xv = xb[(size_t)g * N_];
      a1 = fmaf(s1[g], xv, a1);
      a2 = fmaf(s2[g], xv, a2);
    }
    e1[(size_t)bp * N_ + n] = c1 + a1;
    e2[(size_t)bp * N_ + n] = c2 + a2;
  } else if (blk < 256) {
    // ---- fwbf cast, tiled: one block per tile (p, mb, kb) ----
    int tile = blk - 128;            // 0..127
    int p = tile >> 5;
    int mb = (tile >> 4) & 1;
    int kb = tile & 15;
    int w = t >> 6, lane = t & 63;
    size_t tbase = ((size_t)(p * 2 + mb) * 16 + kb) * 8192;
#pragma unroll
    for (int q = 0; q < 4; ++q) {
      int cell = q * 4 + w;
      int f = mb * 128 + (cell >> 1) * 16 + (lane & 15);
      int kg = kb * 64 + (cell & 1) * 32 + (lane >> 4) * 8;
      const float* s = fw + ((size_t)p * F_ + f) * KG_ + kg;
      float4 v0 = *(const float4*)&s[0];
      float4 v1 = *(const float4*)&s[4];
      u16x8 o;
      o[0] = f2bf(v0.x); o[1] = f2bf(v0.y); o[2] = f2bf(v0.z); o[3] = f2bf(v0.w);
      o[4] = f2bf(v1.x); o[5] = f2bf(v1.y); o[6] = f2bf(v1.z); o[7] = f2bf(v1.w);
      *(u16x8*)&fwbf[tbase + (size_t)cell * 512 + lane * 8] = o;
    }
  } else if (blk < 768) {
    // ---- xT transpose+cast, tiled output ----
    __shared__ ushort_t tile[64][66];
    int idx = blk - 256;
    int n0 = (idx & 15) * 64;
    int g0 = ((idx >> 4) & 3) * 64;
    int b = idx >> 6;
    int rr = t >> 4, cc = (t & 15) * 4;
#pragma unroll
    for (int ps = 0; ps < 4; ++ps) {
      float4 v = *(const float4*)&x[((size_t)b * G_ + g0 + ps * 16 + rr) * N_ + n0 + cc];
      tile[ps * 16 + rr][cc] = f2bf(v.x);
      tile[ps * 16 + rr][cc + 1] = f2bf(v.y);
      tile[ps * 16 + rr][cc + 2] = f2bf(v.z);
      tile[ps * 16 + rr][cc + 3] = f2bf(v.w);
    }
    __syncthreads();
    int w = t >> 6, lane = t & 63;
    int nb = n0 >> 7;                 // 0..7
    int kb = g0 >> 6;                 // 0..3
    int rhalf = (n0 & 64) >> 4;       // 0 or 4
    size_t tbase = ((size_t)(b * 8 + nb) * 4 + kb) * 8192;
#pragma unroll
    for (int q = 0; q < 2; ++q) {
      int cl = q * 4 + w;                         // 0..7 local cell
      int cell = (rhalf + (cl >> 1)) * 2 + (cl & 1);
      int nl = (cl >> 1) * 16 + (lane & 15);      // 0..63 local n
      int gl = (cl & 1) * 32 + (lane >> 4) * 8;   // 0..56
      u16x8 v;
#pragma unroll
      for (int j = 0; j < 8; ++j) v[j] = tile[gl + j][nl];
      *(u16x8*)&xT[tbase + (size_t)cell * 512 + lane * 8] = v;
    }
  } else {
    int i = (blk - 768) * 256 + t;
    sumb[i] = 0.f;
  }
}

// ---------------------------------------------------------------------------
// K5 v2: one block serves ALL 4 p (S/mask is p-invariant).
//   pass 1: read S chunk ONCE -> 64-bit register mask per thread.
//   p-loop: recompute e-values from LDS e1/e2, reuse mask, tiled dump.
//   S read traffic drops 134 MB -> 33.5 MB.
__global__ __launch_bounds__(256) void k_att(const float* __restrict__ e1,
                                             const float* __restrict__ e2,
                                             const float* __restrict__ S,
                                             ushort_t* __restrict__ expT,
                                             float* __restrict__ sumb) {
  __shared__ ushort_t tile[256][72];   // [j-local][i-local]
  __shared__ float se1[P_][256];
  __shared__ float se2[P_][64];
  int b = blockIdx.z;          // 0..7
  int i0 = blockIdx.y * 64;    // k-dim chunk
  int j0 = blockIdx.x * 256;   // n-dim chunk
  int t = threadIdx.x;
  int rr = t >> 4;
  int cc4 = t & 15;
  int cc = cc4 * 4;

#pragma unroll
  for (int p = 0; p < P_; ++p) {
    int bp = b * 4 + p;
    se1[p][t] = e1[(size_t)bp * N_ + j0 + t];
    if (t < 64) se2[p][t] = e2[(size_t)bp * N_ + i0 + t];
  }
  __syncthreads();

  // ---- pass 1: mask bits (S read once) ----
  const float* Sb = S + (size_t)b * N_ * N_;
  unsigned long long mbits = 0ull;
#pragma unroll
  for (int js = 0; js < 4; ++js) {
#pragma unroll
    for (int ps = 0; ps < 4; ++ps) {
      int il = ps * 16 + rr;
      float4 s4 = *(const float4*)&Sb[(size_t)(i0 + il) * N_ + j0 + js * 64 + cc];
      float sv[4] = {s4.x, s4.y, s4.z, s4.w};
#pragma unroll
      for (int s = 0; s < 4; ++s)
        if (fabsf(sv[s]) > 1e-9f)
          mbits |= 1ull << (js * 16 + ps * 4 + s);
    }
  }

  // ---- per-p compute + dump ----
  int w = t >> 6, lane = t & 63;
  int kb = i0 >> 6;
  for (int p = 0; p < P_; ++p) {
    int bp = b * 4 + p;
    float re2[4];
#pragma unroll
    for (int ps = 0; ps < 4; ++ps) re2[ps] = se2[p][ps * 16 + rr];
    float psum[4] = {0.f, 0.f, 0.f, 0.f};
#pragma unroll
    for (int js = 0; js < 4; ++js) {
      float4 e1q = *(float4*)&se1[p][js * 64 + cc];
      float e1v[4] = {e1q.x, e1q.y, e1q.z, e1q.w};
#pragma unroll
      for (int ps = 0; ps < 4; ++ps) {
        int il = ps * 16 + rr;
#pragma unroll
        for (int s = 0; s < 4; ++s) {
          float v = e1v[s] + re2[ps];
          float l = v >= 0.f ? v : 0.2f * v;
          bool m = (mbits >> (js * 16 + ps * 4 + s)) & 1ull;
          float e = m ? __expf(l) : 0.f;
          psum[ps] += e;
          tile[js * 64 + cc + s][il] = f2bf(e);
        }
      }
    }
#pragma unroll
    for (int mask = 1; mask < 16; mask <<= 1) {
#pragma unroll
      for (int ps = 0; ps < 4; ++ps) psum[ps] += __shfl_xor(psum[ps], mask, 64);
    }
    if (cc4 == 0) {
#pragma unroll
      for (int ps = 0; ps < 4; ++ps)
        atomicAdd(&sumb[(size_t)bp * N_ + i0 + ps * 16 + rr], psum[ps]);
    }
    __syncthreads();
    // dump: tiled layout, wave-contiguous 1 KB global stores
#pragma unroll
    for (int hb = 0; hb < 2; ++hb) {
      size_t tbase = ((size_t)(bp * 8 + (j0 >> 7) + hb) * 16 + kb) * 8192;
#pragma unroll
      for (int q = 0; q < 4; ++q) {
        int cell = q * 4 + w;
        int r = (cell >> 1) * 16 + (lane & 15);
        int il = (cell & 1) * 32 + (lane >> 4) * 8;
        u16x8 v = *(const u16x8*)&tile[hb * 128 + r][il];
        *(u16x8*)&expT[tbase + (size_t)cell * 512 + lane * 8] = v;
      }
    }
    __syncthreads();   // tile reads done before next p overwrites
  }
}

// ---------------------------------------------------------------------------
// K6 v6: 128x128 tile, 4 waves 2x2, BK=64, dbuf, counted vmcnt(8), 2
// blocks/CU, all operands in the global tiled layout.  (unchanged)
__global__ __launch_bounds__(256, 2) void gemm_step(
    const ushort_t* __restrict__ Aprev, const ushort_t* __restrict__ Bt,
    const ushort_t* __restrict__ fwbf, const ushort_t* __restrict__ xT,
    const float* __restrict__ bias, const float* __restrict__ sumb,
    ushort_t* __restrict__ outb, float* __restrict__ outf,
    int kslice, int has_prev, int last) {
  __shared__ ushort_t As[2][8192];   // 16 KB per buf: 16 cells x 1 KB
  __shared__ ushort_t Bs[2][8192];
  // ---- XCD-aware decode: id&7 = xcd, 4 bps per XCD, 16 blocks per bp ----
  int id = blockIdx.x;
  int xcd = id & 7;
  int slot = id >> 3;            // 0..63
  int bp = xcd * 4 + (slot >> 4);
  int inner = slot & 15;
  int mb = inner >> 3;           // 0..1
  int m0 = mb * 128;
  int nb = inner & 7;            // 0..7
  int n0 = nb * 128;
  int p = bp & (P_ - 1), b = bp >> 2;
  int t = threadIdx.x;
  int lane = t & 63;
  int w = t >> 6;                // 0..3
  int wm = w >> 1, wn = w & 1;   // 2x2 wave grid, wave tile 64x64
  int lr = lane & 15, quad = lane >> 4;

  // tiled bases (ushort offsets); per k-step add it*8192
  const ushort_t* A1 = has_prev ? (Aprev + (size_t)(bp * 2 + mb) * 16 * 8192) : fwbf;
  const ushort_t* A2 = fwbf + ((size_t)(p * 2 + mb) * 16 + kslice * 4) * 8192;
  const ushort_t* B1 = Bt + (size_t)(bp * 8 + nb) * 16 * 8192;
  const ushort_t* B2 = xT + (size_t)(b * 8 + nb) * 4 * 8192;

  const int ntA = has_prev ? (N_ / 64) : 0;   // 16 or 0
  const int NT = ntA + G_ / 64;               // 20 or 4

  f32x4 acc[4][4] = {};

  int laneoff = lane * 8;
  auto stage = [&](int it, int buf) {
    const ushort_t *Ab, *Bb;
    if (it < ntA) {
      Ab = A1 + (size_t)it * 8192;
      Bb = B1 + (size_t)it * 8192;
    } else {
      Ab = A2 + (size_t)(it - ntA) * 8192;
      Bb = B2 + (size_t)(it - ntA) * 8192;
    }
#pragma unroll
    for (int l = 0; l < 4; ++l) {
      int coff = (w * 4 + l) * 512;
      gload_lds16(Ab + coff + laneoff, &As[buf][coff]);
      gload_lds16(Bb + coff + laneoff, &Bs[buf][coff]);
    }
  };

  // prologue: stage tile 0 into buf 0 (8 loads/wave in flight)
  stage(0, 0);
  int cur = 0;
  for (int it = 0; it < NT; ++it) {
    if (it + 1 < NT) {
      stage(it + 1, cur ^ 1);                          // 16 in flight
      asm volatile("s_waitcnt vmcnt(8)" ::: "memory"); // cur tile landed
    } else {
      asm volatile("s_waitcnt vmcnt(0)" ::: "memory");
    }
    __builtin_amdgcn_s_barrier();        // all waves' cur-tile DMA visible
#pragma unroll
    for (int c = 0; c < 2; ++c) {
      bf16x8 af[4], bfr[4];
#pragma unroll
      for (int mi = 0; mi < 4; ++mi)
        af[mi] = __builtin_bit_cast(bf16x8,
            *(const u16x8*)&As[cur][(((wm * 4 + mi) * 2) + c) * 512 + lane * 8]);
#pragma unroll
      for (int ni = 0; ni < 4; ++ni)
        bfr[ni] = __builtin_bit_cast(bf16x8,
            *(const u16x8*)&Bs[cur][(((wn * 4 + ni) * 2) + c) * 512 + lane * 8]);
#pragma unroll
      for (int mi = 0; mi < 4; ++mi)
#pragma unroll
        for (int ni = 0; ni < 4; ++ni)
          acc[mi][ni] = __builtin_amdgcn_mfma_f32_16x16x32_bf16(af[mi], bfr[ni], acc[mi][ni], 0, 0, 0);
    }
    __builtin_amdgcn_s_barrier();        // reads done before buf overwritten
    cur ^= 1;
  }

  if (last) {
    float* Ob = outf + (size_t)bp * (F_ * N_);
#pragma unroll
    for (int mi = 0; mi < 4; ++mi) {
      int fbase = m0 + wm * 64 + mi * 16 + quad * 4;
#pragma unroll
      for (int ni = 0; ni < 4; ++ni) {
        int n = n0 + wn * 64 + ni * 16 + lr;
#pragma unroll
        for (int r = 0; r < 4; ++r) {
          float v = acc[mi][ni][r] + bias[fbase + r];
          Ob[(size_t)(fbase + r) * N_ + n] = v >= 0.f ? v : 0.01f * v;
        }
      }
    }
  } else {
    // epilogue via LDS scratch -> tiled global layout (next step's A)
    ushort_t* scratch = &As[0][0];   // 16384 ushorts = 32 KB
    float iv[4];
#pragma unroll
    for (int ni = 0; ni < 4; ++ni)
      iv[ni] = 1.0f / sumb[(size_t)bp * N_ + n0 + wn * 64 + ni * 16 + lr];
#pragma unroll
    for (int mi = 0; mi < 4; ++mi) {
#pragma unroll
      for (int ni = 0; ni < 4; ++ni) {
        int nL = wn * 64 + ni * 16 + lr;          // block-local n (= k of next A)
        int kbh = nL >> 6;                        // 0 or 1
        int kloc = nL & 63;
        int cellbase = kbh * 8192 +
                       ((wm * 4 + mi) * 2 + (kloc >> 5)) * 512 +
                       (((kloc >> 3) & 3) * 16 + quad * 4) * 8 + (kloc & 7);
#pragma unroll
        for (int r = 0; r < 4; ++r)
          scratch[cellbase + r * 8] = f2bf(acc[mi][ni][r] * iv[ni]);
      }
    }
    __syncthreads();
    size_t obase = ((size_t)(bp * 2 + mb) * 16 + (n0 >> 6)) * 8192;
#pragma unroll
    for (int pass = 0; pass < 8; ++pass) {
      int fl = pass * 2048 + t * 8;
      *(u16x8*)&outb[obase + fl] = *(const u16x8*)&scratch[fl];
    }
  }
}

// ---------------------------------------------------------------------------
extern "C" void kernel_launch(void* const* d_in, const int* in_sizes, int n_in,
                              void* d_out, int out_size, void* d_ws, size_t ws_size,
                              hipStream_t stream) {
  const float* x = (const float*)d_in[0];
  const float* mixer = (const float*)d_in[1];
  const float* weight = (const float*)d_in[2];
  const float* wb = (const float*)d_in[3];
  const float* fw = (const float*)d_in[4];
  const float* bias = (const float*)d_in[5];
  const float* S = (const float*)d_in[6];
  float* out = (float*)d_out;

  char* ws = (char*)d_ws;
  size_t off = 0;
  auto take = [&](size_t bytes) -> char* {
    char* p = ws + off;
    off = (off + bytes + 255) & ~(size_t)255;
    return p;
  };
  float* e1 = (float*)take((size_t)B_ * P_ * N_ * 4);
  float* e2 = (float*)take((size_t)B_ * P_ * N_ * 4);
  float* sumb = (float*)take((size_t)B_ * P_ * N_ * 4);
  ushort_t* fwbf = (ushort_t*)take((size_t)P_ * F_ * KHOP * G_ * 2);
  ushort_t* xT = (ushort_t*)take((size_t)B_ * N_ * G_ * 2);
  ushort_t* expT = (ushort_t*)take((size_t)B_ * P_ * N_ * N_ * 2);
  ushort_t* sA = (ushort_t*)take((size_t)B_ * P_ * F_ * N_ * 2);
  ushort_t* sB = (ushort_t*)take((size_t)B_ * P_ * F_ * N_ * 2);

  k_prep<<<896, 256, 0, stream>>>(x, mixer, weight, wb, fw, e1, e2, fwbf, xT, sumb);
  k_att<<<dim3(4, 16, 8), 256, 0, stream>>>(e1, e2, S, expT, sumb);

  // Horner (1/rowsum folded into stored intermediates):
  // s3' = (fw3*x) . inv ; s2' = (s3'*E^T + fw2*x) . inv ;
  // s1' = (s2'*E^T + fw1*x) . inv ; out = lrelu(s1'*E^T + fw0*x + bias)
  gemm_step<<<512, 256, 0, stream>>>(nullptr, expT, fwbf, xT, bias, sumb, sA, nullptr, 3, 0, 0);
  gemm_step<<<512, 256, 0, stream>>>(sA, expT, fwbf, xT, bias, sumb, sB, nullptr, 2, 1, 0);
  gemm_step<<<512, 256, 0, stream>>>(sB, expT, fwbf, xT, bias, sumb, sA, nullptr, 1, 1, 0);
  gemm_step<<<512, 256, 0, stream>>>(sA, expT, fwbf, xT, bias, sumb, nullptr, out, 0, 1, 1);
}

// Round 7
// 225.386 us; speedup vs baseline: 1.2707x; 1.0065x over previous
//
#include <hip/hip_runtime.h>
#include <hip/hip_bf16.h>

#define B_ 8
#define G_ 256
#define N_ 1024
#define P_ 4
#define F_ 256
#define KHOP 4
#define KG_ (KHOP * G_)   // 1024

// ---------------------------------------------------------------------------
// GLOBAL TILED LAYOUT (shared by expT, fwbf, xT, sA/sB):
//   matrix [R rows][C k-cols] -> tiles [R/128][C/64], each tile 8192 ushorts
//   (16 KB) contiguous.  Within a tile, element (r,k), r<128, k<64:
//     cell = (r>>4)*2 + (k>>5)            [0..15]
//     lane = ((k>>3)&3)*16 + (r&15)       [0..63]
//     e    = k&7
//     flat = cell*512 + lane*8 + e
//   One cell = one 16x32 MFMA fragment in exact lane order.
//   A-side consequence: a wave can load its MFMA A-fragment DIRECTLY from
//   global (1 contiguous 1 KB read) -- no LDS round-trip needed.
// ---------------------------------------------------------------------------

typedef unsigned short ushort_t;
typedef __bf16 bf16x8 __attribute__((ext_vector_type(8)));
typedef unsigned short u16x8 __attribute__((ext_vector_type(8)));
typedef float f32x4 __attribute__((ext_vector_type(4)));

__device__ __forceinline__ unsigned short f2bf(float f) {
  union { float fl; unsigned int i; } v; v.fl = f;
  return (unsigned short)((v.i + 0x7fffu + ((v.i >> 16) & 1u)) >> 16);
}

__device__ __forceinline__ void gload_lds16(const ushort_t* g, ushort_t* l) {
  __builtin_amdgcn_global_load_lds(
      (const __attribute__((address_space(1))) void*)g,
      (__attribute__((address_space(3))) void*)l, 16, 0, 0);
}

// ---------------------------------------------------------------------------
// K-PREP: block ranges: [0,128) e1/e2 | [128,256) fwbf tiled cast |
// [256,768) xT transpose+tiled | [768,896) zero sumb.   (unchanged)
__global__ __launch_bounds__(256) void k_prep(
    const float* __restrict__ x, const float* __restrict__ mixer,
    const float* __restrict__ weight, const float* __restrict__ wb,
    const float* __restrict__ fw, float* __restrict__ e1, float* __restrict__ e2,
    ushort_t* __restrict__ fwbf, ushort_t* __restrict__ xT,
    float* __restrict__ sumb) {
  int blk = blockIdx.x;
  int t = threadIdx.x;
  if (blk < 128) {
    __shared__ float s1[G_], s2[G_];
    __shared__ float cred[2][4];
    int bp = blk >> 2;
    int nc = blk & 3;
    int b = bp >> 2, p = bp & (P_ - 1);
    int n = nc * 256 + t;
    float acc1 = 0.f, acc2 = 0.f;
    const float* wp = weight + (size_t)p * F_ * G_ + t;
    const float* mp = mixer + p * 2 * F_;
    for (int f = 0; f < F_; ++f) {
      float wv = wp[(size_t)f * G_];
      acc1 = fmaf(mp[f], wv, acc1);
      acc2 = fmaf(mp[F_ + f], wv, acc2);
    }
    s1[t] = acc1;
    s2[t] = acc2;
    float c1p = mp[t] * wb[p * F_ + t];
    float c2p = mp[F_ + t] * wb[p * F_ + t];
#pragma unroll
    for (int mask = 1; mask < 64; mask <<= 1) {
      c1p += __shfl_xor(c1p, mask, 64);
      c2p += __shfl_xor(c2p, mask, 64);
    }
    if ((t & 63) == 0) {
      cred[0][t >> 6] = c1p;
      cred[1][t >> 6] = c2p;
    }
    __syncthreads();
    float c1 = cred[0][0] + cred[0][1] + cred[0][2] + cred[0][3];
    float c2 = cred[1][0] + cred[1][1] + cred[1][2] + cred[1][3];
    const float* xb = x + (size_t)b * G_ * N_ + n;
    float a1 = 0.f, a2 = 0.f;
#pragma unroll 8
    for (int g = 0; g < G_; ++g) {
      float xv = xb[(size_t)g * N_];
      a1 = fmaf(s1[g], xv, a1);
      a2 = fmaf(s2[g], xv, a2);
    }
    e1[(size_t)bp * N_ + n] = c1 + a1;
    e2[(size_t)bp * N_ + n] = c2 + a2;
  } else if (blk < 256) {
    // ---- fwbf cast, tiled: one block per tile (p, mb, kb) ----
    int tile = blk - 128;            // 0..127
    int p = tile >> 5;
    int mb = (tile >> 4) & 1;
    int kb = tile & 15;
    int w = t >> 6, lane = t & 63;
    size_t tbase = ((size_t)(p * 2 + mb) * 16 + kb) * 8192;
#pragma unroll
    for (int q = 0; q < 4; ++q) {
      int cell = q * 4 + w;
      int f = mb * 128 + (cell >> 1) * 16 + (lane & 15);
      int kg = kb * 64 + (cell & 1) * 32 + (lane >> 4) * 8;
      const float* s = fw + ((size_t)p * F_ + f) * KG_ + kg;
      float4 v0 = *(const float4*)&s[0];
      float4 v1 = *(const float4*)&s[4];
      u16x8 o;
      o[0] = f2bf(v0.x); o[1] = f2bf(v0.y); o[2] = f2bf(v0.z); o[3] = f2bf(v0.w);
      o[4] = f2bf(v1.x); o[5] = f2bf(v1.y); o[6] = f2bf(v1.z); o[7] = f2bf(v1.w);
      *(u16x8*)&fwbf[tbase + (size_t)cell * 512 + lane * 8] = o;
    }
  } else if (blk < 768) {
    // ---- xT transpose+cast, tiled output ----
    __shared__ ushort_t tile[64][66];
    int idx = blk - 256;
    int n0 = (idx & 15) * 64;
    int g0 = ((idx >> 4) & 3) * 64;
    int b = idx >> 6;
    int rr = t >> 4, cc = (t & 15) * 4;
#pragma unroll
    for (int ps = 0; ps < 4; ++ps) {
      float4 v = *(const float4*)&x[((size_t)b * G_ + g0 + ps * 16 + rr) * N_ + n0 + cc];
      tile[ps * 16 + rr][cc] = f2bf(v.x);
      tile[ps * 16 + rr][cc + 1] = f2bf(v.y);
      tile[ps * 16 + rr][cc + 2] = f2bf(v.z);
      tile[ps * 16 + rr][cc + 3] = f2bf(v.w);
    }
    __syncthreads();
    int w = t >> 6, lane = t & 63;
    int nb = n0 >> 7;                 // 0..7
    int kb = g0 >> 6;                 // 0..3
    int rhalf = (n0 & 64) >> 4;       // 0 or 4
    size_t tbase = ((size_t)(b * 8 + nb) * 4 + kb) * 8192;
#pragma unroll
    for (int q = 0; q < 2; ++q) {
      int cl = q * 4 + w;                         // 0..7 local cell
      int cell = (rhalf + (cl >> 1)) * 2 + (cl & 1);
      int nl = (cl >> 1) * 16 + (lane & 15);      // 0..63 local n
      int gl = (cl & 1) * 32 + (lane >> 4) * 8;   // 0..56
      u16x8 v;
#pragma unroll
      for (int j = 0; j < 8; ++j) v[j] = tile[gl + j][nl];
      *(u16x8*)&xT[tbase + (size_t)cell * 512 + lane * 8] = v;
    }
  } else {
    int i = (blk - 768) * 256 + t;
    sumb[i] = 0.f;
  }
}

// ---------------------------------------------------------------------------
// K5 v2: one block serves ALL 4 p (S/mask read once).  (unchanged)
__global__ __launch_bounds__(256) void k_att(const float* __restrict__ e1,
                                             const float* __restrict__ e2,
                                             const float* __restrict__ S,
                                             ushort_t* __restrict__ expT,
                                             float* __restrict__ sumb) {
  __shared__ ushort_t tile[256][72];   // [j-local][i-local]
  __shared__ float se1[P_][256];
  __shared__ float se2[P_][64];
  int b = blockIdx.z;          // 0..7
  int i0 = blockIdx.y * 64;    // k-dim chunk
  int j0 = blockIdx.x * 256;   // n-dim chunk
  int t = threadIdx.x;
  int rr = t >> 4;
  int cc4 = t & 15;
  int cc = cc4 * 4;

#pragma unroll
  for (int p = 0; p < P_; ++p) {
    int bp = b * 4 + p;
    se1[p][t] = e1[(size_t)bp * N_ + j0 + t];
    if (t < 64) se2[p][t] = e2[(size_t)bp * N_ + i0 + t];
  }
  __syncthreads();

  // ---- pass 1: mask bits (S read once) ----
  const float* Sb = S + (size_t)b * N_ * N_;
  unsigned long long mbits = 0ull;
#pragma unroll
  for (int js = 0; js < 4; ++js) {
#pragma unroll
    for (int ps = 0; ps < 4; ++ps) {
      int il = ps * 16 + rr;
      float4 s4 = *(const float4*)&Sb[(size_t)(i0 + il) * N_ + j0 + js * 64 + cc];
      float sv[4] = {s4.x, s4.y, s4.z, s4.w};
#pragma unroll
      for (int s = 0; s < 4; ++s)
        if (fabsf(sv[s]) > 1e-9f)
          mbits |= 1ull << (js * 16 + ps * 4 + s);
    }
  }

  // ---- per-p compute + dump ----
  int w = t >> 6, lane = t & 63;
  int kb = i0 >> 6;
  for (int p = 0; p < P_; ++p) {
    int bp = b * 4 + p;
    float re2[4];
#pragma unroll
    for (int ps = 0; ps < 4; ++ps) re2[ps] = se2[p][ps * 16 + rr];
    float psum[4] = {0.f, 0.f, 0.f, 0.f};
#pragma unroll
    for (int js = 0; js < 4; ++js) {
      float4 e1q = *(float4*)&se1[p][js * 64 + cc];
      float e1v[4] = {e1q.x, e1q.y, e1q.z, e1q.w};
#pragma unroll
      for (int ps = 0; ps < 4; ++ps) {
        int il = ps * 16 + rr;
#pragma unroll
        for (int s = 0; s < 4; ++s) {
          float v = e1v[s] + re2[ps];
          float l = v >= 0.f ? v : 0.2f * v;
          bool m = (mbits >> (js * 16 + ps * 4 + s)) & 1ull;
          float e = m ? __expf(l) : 0.f;
          psum[ps] += e;
          tile[js * 64 + cc + s][il] = f2bf(e);
        }
      }
    }
#pragma unroll
    for (int mask = 1; mask < 16; mask <<= 1) {
#pragma unroll
      for (int ps = 0; ps < 4; ++ps) psum[ps] += __shfl_xor(psum[ps], mask, 64);
    }
    if (cc4 == 0) {
#pragma unroll
      for (int ps = 0; ps < 4; ++ps)
        atomicAdd(&sumb[(size_t)bp * N_ + i0 + ps * 16 + rr], psum[ps]);
    }
    __syncthreads();
    // dump: tiled layout, wave-contiguous 1 KB global stores
#pragma unroll
    for (int hb = 0; hb < 2; ++hb) {
      size_t tbase = ((size_t)(bp * 8 + (j0 >> 7) + hb) * 16 + kb) * 8192;
#pragma unroll
      for (int q = 0; q < 4; ++q) {
        int cell = q * 4 + w;
        int r = (cell >> 1) * 16 + (lane & 15);
        int il = (cell & 1) * 32 + (lane >> 4) * 8;
        u16x8 v = *(const u16x8*)&tile[hb * 128 + r][il];
        *(u16x8*)&expT[tbase + (size_t)cell * 512 + lane * 8] = v;
      }
    }
    __syncthreads();   // tile reads done before next p overwrites
  }
}

// ---------------------------------------------------------------------------
// K6 v7: A DIRECT FROM GLOBAL (frag-ordered tiled layout = one contiguous
// 1 KB global_load_dwordx4 per A-fragment, L2-resident on home XCD).
// Only B goes through LDS (32 KB/block double-buffered) -> 3 blocks/CU.
// Per iter: issue 8 afr loads (oldest after B_cur) -> sched_barrier pins
// order -> stage B_next (4 DMA) -> vmcnt(12) = B_cur landed (afr + B_next
// still in flight; compiler's own wait before afr use is vmcnt(4), leaving
// B_next in flight) -> barrier -> 8 ds_read + 32 MFMA -> barrier.
__global__ __launch_bounds__(256, 3) void gemm_step(
    const ushort_t* __restrict__ Aprev, const ushort_t* __restrict__ Bt,
    const ushort_t* __restrict__ fwbf, const ushort_t* __restrict__ xT,
    const float* __restrict__ bias, const float* __restrict__ sumb,
    ushort_t* __restrict__ outb, float* __restrict__ outf,
    int kslice, int has_prev, int last) {
  __shared__ ushort_t Bs[2][8192];   // 16 KB per buf
  // ---- XCD-aware decode: id&7 = xcd, 4 bps per XCD, 16 blocks per bp ----
  int id = blockIdx.x;
  int xcd = id & 7;
  int slot = id >> 3;            // 0..63
  int bp = xcd * 4 + (slot >> 4);
  int inner = slot & 15;
  int mb = inner >> 3;           // 0..1
  int m0 = mb * 128;
  int nb = inner & 7;            // 0..7
  int n0 = nb * 128;
  int p = bp & (P_ - 1), b = bp >> 2;
  int t = threadIdx.x;
  int lane = t & 63;
  int w = t >> 6;                // 0..3
  int wm = w >> 1, wn = w & 1;   // 2x2 wave grid, wave tile 64x64
  int lr = lane & 15, quad = lane >> 4;

  // tiled bases (ushort offsets); per k-step add it*8192
  const ushort_t* A1 = has_prev ? (Aprev + (size_t)(bp * 2 + mb) * 16 * 8192) : fwbf;
  const ushort_t* A2 = fwbf + ((size_t)(p * 2 + mb) * 16 + kslice * 4) * 8192;
  const ushort_t* B1 = Bt + (size_t)(bp * 8 + nb) * 16 * 8192;
  const ushort_t* B2 = xT + (size_t)(b * 8 + nb) * 4 * 8192;

  const int ntA = has_prev ? (N_ / 64) : 0;   // 16 or 0
  const int NT = ntA + G_ / 64;               // 20 or 4

  f32x4 acc[4][4] = {};
  int laneoff = lane * 8;

  auto stageB = [&](int it, int buf) {
    const ushort_t* Bb = (it < ntA) ? B1 + (size_t)it * 8192
                                    : B2 + (size_t)(it - ntA) * 8192;
#pragma unroll
    for (int l = 0; l < 4; ++l) {
      int coff = (w * 4 + l) * 512;
      gload_lds16(Bb + coff + laneoff, &Bs[buf][coff]);
    }
  };

  // prologue: stage B tile 0 into buf 0 (4 loads/wave in flight)
  stageB(0, 0);
  int cur = 0;
  for (int it = 0; it < NT; ++it) {
    const ushort_t* At = (it < ntA) ? A1 + (size_t)it * 8192
                                    : A2 + (size_t)(it - ntA) * 8192;
    // A fragments: direct global->VGPR (wave-contiguous 1 KB each)
    u16x8 afr[2][4];
#pragma unroll
    for (int c = 0; c < 2; ++c)
#pragma unroll
      for (int mi = 0; mi < 4; ++mi)
        afr[c][mi] = *(const u16x8*)&At[(((wm * 4 + mi) * 2) + c) * 512 + laneoff];
    __builtin_amdgcn_sched_barrier(0);   // pin: afr issued before B_next DMA
    if (it + 1 < NT) {
      stageB(it + 1, cur ^ 1);                          // 4 more in flight
      asm volatile("s_waitcnt vmcnt(12)" ::: "memory"); // B_cur landed
    } else {
      asm volatile("s_waitcnt vmcnt(0)" ::: "memory");
    }
    __builtin_amdgcn_s_barrier();        // all waves' B_cur DMA visible
#pragma unroll
    for (int c = 0; c < 2; ++c) {
      bf16x8 bfr[4];
#pragma unroll
      for (int ni = 0; ni < 4; ++ni)
        bfr[ni] = __builtin_bit_cast(bf16x8,
            *(const u16x8*)&Bs[cur][(((wn * 4 + ni) * 2) + c) * 512 + lane * 8]);
#pragma unroll
      for (int mi = 0; mi < 4; ++mi) {
        bf16x8 af = __builtin_bit_cast(bf16x8, afr[c][mi]);
#pragma unroll
        for (int ni = 0; ni < 4; ++ni)
          acc[mi][ni] = __builtin_amdgcn_mfma_f32_16x16x32_bf16(af, bfr[ni], acc[mi][ni], 0, 0, 0);
      }
    }
    __builtin_amdgcn_s_barrier();        // reads done before buf overwritten
    cur ^= 1;
  }

  if (last) {
    float* Ob = outf + (size_t)bp * (F_ * N_);
#pragma unroll
    for (int mi = 0; mi < 4; ++mi) {
      int fbase = m0 + wm * 64 + mi * 16 + quad * 4;
#pragma unroll
      for (int ni = 0; ni < 4; ++ni) {
        int n = n0 + wn * 64 + ni * 16 + lr;
#pragma unroll
        for (int r = 0; r < 4; ++r) {
          float v = acc[mi][ni][r] + bias[fbase + r];
          Ob[(size_t)(fbase + r) * N_ + n] = v >= 0.f ? v : 0.01f * v;
        }
      }
    }
  } else {
    // epilogue via LDS scratch -> tiled global layout (next step's A)
    ushort_t* scratch = &Bs[0][0];   // 16384 ushorts = 32 KB
    float iv[4];
#pragma unroll
    for (int ni = 0; ni < 4; ++ni)
      iv[ni] = 1.0f / sumb[(size_t)bp * N_ + n0 + wn * 64 + ni * 16 + lr];
#pragma unroll
    for (int mi = 0; mi < 4; ++mi) {
#pragma unroll
      for (int ni = 0; ni < 4; ++ni) {
        int nL = wn * 64 + ni * 16 + lr;          // block-local n (= k of next A)
        int kbh = nL >> 6;                        // 0 or 1
        int kloc = nL & 63;
        int cellbase = kbh * 8192 +
                       ((wm * 4 + mi) * 2 + (kloc >> 5)) * 512 +
                       (((kloc >> 3) & 3) * 16 + quad * 4) * 8 + (kloc & 7);
#pragma unroll
        for (int r = 0; r < 4; ++r)
          scratch[cellbase + r * 8] = f2bf(acc[mi][ni][r] * iv[ni]);
      }
    }
    __syncthreads();
    size_t obase = ((size_t)(bp * 2 + mb) * 16 + (n0 >> 6)) * 8192;
#pragma unroll
    for (int pass = 0; pass < 8; ++pass) {
      int fl = pass * 2048 + t * 8;
      *(u16x8*)&outb[obase + fl] = *(const u16x8*)&scratch[fl];
    }
  }
}

// ---------------------------------------------------------------------------
extern "C" void kernel_launch(void* const* d_in, const int* in_sizes, int n_in,
                              void* d_out, int out_size, void* d_ws, size_t ws_size,
                              hipStream_t stream) {
  const float* x = (const float*)d_in[0];
  const float* mixer = (const float*)d_in[1];
  const float* weight = (const float*)d_in[2];
  const float* wb = (const float*)d_in[3];
  const float* fw = (const float*)d_in[4];
  const float* bias = (const float*)d_in[5];
  const float* S = (const float*)d_in[6];
  float* out = (float*)d_out;

  char* ws = (char*)d_ws;
  size_t off = 0;
  auto take = [&](size_t bytes) -> char* {
    char* p = ws + off;
    off = (off + bytes + 255) & ~(size_t)255;
    return p;
  };
  float* e1 = (float*)take((size_t)B_ * P_ * N_ * 4);
  float* e2 = (float*)take((size_t)B_ * P_ * N_ * 4);
  float* sumb = (float*)take((size_t)B_ * P_ * N_ * 4);
  ushort_t* fwbf = (ushort_t*)take((size_t)P_ * F_ * KHOP * G_ * 2);
  ushort_t* xT = (ushort_t*)take((size_t)B_ * N_ * G_ * 2);
  ushort_t* expT = (ushort_t*)take((size_t)B_ * P_ * N_ * N_ * 2);
  ushort_t* sA = (ushort_t*)take((size_t)B_ * P_ * F_ * N_ * 2);
  ushort_t* sB = (ushort_t*)take((size_t)B_ * P_ * F_ * N_ * 2);

  k_prep<<<896, 256, 0, stream>>>(x, mixer, weight, wb, fw, e1, e2, fwbf, xT, sumb);
  k_att<<<dim3(4, 16, 8), 256, 0, stream>>>(e1, e2, S, expT, sumb);

  // Horner (1/rowsum folded into stored intermediates):
  // s3' = (fw3*x) . inv ; s2' = (s3'*E^T + fw2*x) . inv ;
  // s1' = (s2'*E^T + fw1*x) . inv ; out = lrelu(s1'*E^T + fw0*x + bias)
  gemm_step<<<512, 256, 0, stream>>>(nullptr, expT, fwbf, xT, bias, sumb, sA, nullptr, 3, 0, 0);
  gemm_step<<<512, 256, 0, stream>>>(sA, expT, fwbf, xT, bias, sumb, sB, nullptr, 2, 1, 0);
  gemm_step<<<512, 256, 0, stream>>>(sB, expT, fwbf, xT, bias, sumb, sA, nullptr, 1, 1, 0);
  gemm_step<<<512, 256, 0, stream>>>(sA, expT, fwbf, xT, bias, sumb, nullptr, out, 0, 1, 1);
}